// Round 1
// baseline (692.297 us; speedup 1.0000x reference)
//
#include <hip/hip_runtime.h>

// ProdAt: x[B=16384, 128*64=8192] fp32 -> out[B,128] fp32,
// out[b,s] = prod_{l<64} x[b, s*64+l].
//
// Memory-bound: 512 MiB read / 8 MiB write -> ~85 us floor @ 6.3 TB/s.
// Wave-aligned 16B loads (16 B/lane, unit stride), 16-lane shfl_xor product
// tree, one store per segment.
//
// This revision (vs 650 us best):
//  - DROP nontemporal loads. Theory: nt (no-allocate) policy on gfx950
//    throttles the streaming read path to ~1.7 TB/s; the plain-load path is
//    what the 6.3 TB/s copy ubench uses. The harness fill in the same capture
//    sustains 6.4 TB/s, so the chip BW is there.
//  - Explicit 2-phase batches: issue 8 independent global_load_dwordx4 into
//    v[8] before any consumer, so 8 loads are in flight per wave before the
//    first s_waitcnt vmcnt, independent of compiler scheduling of the
//    shfl/store tail. 8x16B data regs = 32 VGPR, keeps full occupancy.

typedef float floatx4 __attribute__((ext_vector_type(4)));

#define GRID   4096
#define BLOCK  256
#define NTHREADS ((long long)GRID * BLOCK)       // 1,048,576 threads
#define OUTER  4
#define INNER  8                                  // OUTER*INNER = 32 float4/thread

__global__ __launch_bounds__(BLOCK) void prodat_kernel(
    const floatx4* __restrict__ x4, float* __restrict__ out) {
    const long long tid = (long long)blockIdx.x * BLOCK + threadIdx.x;
    const int lane = threadIdx.x & 63;

    for (int ot = 0; ot < OUTER; ++ot) {
        const long long base = tid + (long long)ot * INNER * NTHREADS;

        floatx4 v[INNER];
#pragma unroll
        for (int u = 0; u < INNER; ++u) {
            v[u] = x4[base + (long long)u * NTHREADS];
        }

#pragma unroll
        for (int u = 0; u < INNER; ++u) {
            float p = (v[u].x * v[u].y) * (v[u].z * v[u].w);
            // product across the 16-lane group covering one 64-elem segment
            p *= __shfl_xor(p, 1);
            p *= __shfl_xor(p, 2);
            p *= __shfl_xor(p, 4);
            p *= __shfl_xor(p, 8);
            if ((lane & 15) == 0) {
                out[(base + (long long)u * NTHREADS) >> 4] = p;  // float4 idx -> segment idx
            }
        }
    }
}

extern "C" void kernel_launch(void* const* d_in, const int* in_sizes, int n_in,
                              void* d_out, int out_size, void* d_ws, size_t ws_size,
                              hipStream_t stream) {
    const floatx4* x4 = (const floatx4*)d_in[0];
    float* out = (float*)d_out;
    // in_sizes[0] == 16384*8192 == GRID*BLOCK*OUTER*INNER*4, exact — no tail.
    prodat_kernel<<<GRID, BLOCK, 0, stream>>>(x4, out);
}

// Round 2
// 653.217 us; speedup vs baseline: 1.0598x; 1.0598x over previous
//
#include <hip/hip_runtime.h>

// ProdAt: x[B=16384, 128*64=8192] fp32 -> out[B,128] fp32,
// out[b,s] = prod_{l<64} x[b, s*64+l].
//
// Memory-bound: 512 MiB read / 8 MiB write -> ~85 us floor @ 6.3 TB/s.
//
// Round-0 base (650 us, best so far): nt dwordx4 loads (512 MiB single-use
// stream, 2x L3 -> no-allocate wins; A/B-verified vs plain loads, +42 us
// without), interleaved #pragma unroll 8, 16B/lane wave-aligned loads.
//
// This revision, ONE variable vs round 0:
//  - Replace the 4-step __shfl_xor product tree (ds_swizzle_b32 on the LDS
//    pipe, 4 dependent lgkmcnt waits per iteration, ~60-120 cy each) with a
//    VALU-only DPP row-rotation tree: row_ror:1/2/4/8 within the 16-lane DPP
//    row. Combining rotations 1,2,4,8 gives every lane the product of all 16
//    lanes of its row; rows (lanes 0-15,16-31,...) exactly match our
//    16-float4 = one-segment groups. Zero LDS-pipe ops, zero lgkm waits ->
//    the loop's only waits are vmcnt, like the 6.3 TB/s copy ubench.
//  - (free) nontemporal store for the 8 MiB output.

typedef float floatx4 __attribute__((ext_vector_type(4)));

#define GRID   4096
#define BLOCK  256
#define NTHREADS ((long long)GRID * BLOCK)       // 1,048,576
#define ITERS  32                                 // 33,554,432 float4s total

// p *= (value of p from lane (i+N) mod 16 within the DPP row of 16).
// DPP ctrl: row_ror:N = 0x120+N.
template <int CTRL>
__device__ __forceinline__ float ror_mul(float p) {
    int xi = __builtin_bit_cast(int, p);
    int yi = __builtin_amdgcn_update_dpp(0, xi, CTRL, 0xf, 0xf, true);
    return p * __builtin_bit_cast(float, yi);
}

__global__ __launch_bounds__(BLOCK) void prodat_kernel(
    const floatx4* __restrict__ x4, float* __restrict__ out) {
    const long long tid = (long long)blockIdx.x * BLOCK + threadIdx.x;
    const int lane = threadIdx.x & 63;

#pragma unroll 8
    for (int it = 0; it < ITERS; ++it) {
        const long long i = tid + (long long)it * NTHREADS;
        floatx4 v = __builtin_nontemporal_load(&x4[i]);
        float p = (v.x * v.y) * (v.z * v.w);
        // product across the 16-lane DPP row covering one 64-elem segment:
        // rotations by 1,2,4,8 fold all 16 lanes into every lane.
        p = ror_mul<0x121>(p);  // row_ror:1
        p = ror_mul<0x122>(p);  // row_ror:2
        p = ror_mul<0x124>(p);  // row_ror:4
        p = ror_mul<0x128>(p);  // row_ror:8
        if ((lane & 15) == 0) {
            __builtin_nontemporal_store(p, &out[i >> 4]);  // float4 idx -> segment idx
        }
    }
}

extern "C" void kernel_launch(void* const* d_in, const int* in_sizes, int n_in,
                              void* d_out, int out_size, void* d_ws, size_t ws_size,
                              hipStream_t stream) {
    const floatx4* x4 = (const floatx4*)d_in[0];
    float* out = (float*)d_out;
    // in_sizes[0] == 16384*8192 == GRID*BLOCK*ITERS*4, exact — no tail.
    prodat_kernel<<<GRID, BLOCK, 0, stream>>>(x4, out);
}

// Round 4
// 643.410 us; speedup vs baseline: 1.0760x; 1.0152x over previous
//
#include <hip/hip_runtime.h>

// ProdAt: x[B=16384, 128*64=8192] fp32 -> out[B,128] fp32,
// out[b,s] = prod_{l<64} x[b, s*64+l].
//
// Memory-bound: 512 MiB read / 8 MiB write -> ~85 us kernel floor @ 6.3 TB/s.
//
// Session model (r0-r2 evidence): the timed graph = harness reset (2 GiB
// poison fill ~336 us @6.4 TB/s + restore/memset dispatches ~200 us) + this
// kernel (~95 us). Round-1's plain-load A/B refutes "kernel ~314 us": a
// plain coalesced float4 stream cannot run at 1.5 TB/s while fills in the
// same capture sustain 6.4 TB/s.
//
// Proven best config, kept: nt dwordx4 loads (single-use 512 MiB stream, 2x
// L3 -> no-allocate wins, +42 us without), interleaved #pragma unroll 8,
// VALU-only DPP row_ror product tree (LDS pipe idle), nt store.
//
// This revision, ONE variable: 32-bit saddr addressing. Input span 512 MiB
// < 2^31, so every address is SGPR-base + u32 voffset
// (global_load_dwordx4 v[..], v_off, s[b:b+1]) — drops the per-load 64-bit
// v_lshl_add_u64 pairs and halves address VGPRs. Decisive probe: neutral
// result confirms the kernel is at its memory roofline (declare next round);
// >15 us gain means address gen was throttling the stream.
//
// (Round-3 bench was an infra failure — container died twice, no data —
// this is an unchanged resubmit of the round-2 probe.)

typedef float floatx4 __attribute__((ext_vector_type(4)));

#define GRID   4096
#define BLOCK  256
#define NTHREADS (GRID * BLOCK)                  // 1,048,576 threads
#define ITERS  32                                 // 33,554,432 float4s total

// p *= (value of p from lane (i+N) mod 16 within the DPP row of 16).
// DPP ctrl: row_ror:N = 0x120+N. Rows of 16 lanes == one 64-elem segment.
template <int CTRL>
__device__ __forceinline__ float ror_mul(float p) {
    int xi = __builtin_bit_cast(int, p);
    int yi = __builtin_amdgcn_update_dpp(0, xi, CTRL, 0xf, 0xf, true);
    return p * __builtin_bit_cast(float, yi);
}

__global__ __launch_bounds__(BLOCK) void prodat_kernel(
    const char* __restrict__ xb, char* __restrict__ outb) {
    const unsigned tid = blockIdx.x * BLOCK + threadIdx.x;   // < 2^20
    const unsigned xoff0 = tid * 16u;                        // byte offset
    const unsigned ooff0 = (tid >> 4) * 4u;                  // byte offset
    const bool store_lane = (threadIdx.x & 15) == 0;

#pragma unroll 8
    for (int it = 0; it < ITERS; ++it) {
        // max xoff = 16*(2^20-1) + 31*16 MiB = 520,093,680 < 2^31: u32-safe
        const unsigned xoff = xoff0 + (unsigned)it * (16u * NTHREADS);
        floatx4 v = __builtin_nontemporal_load(
            (const floatx4*)(xb + xoff));
        float p = (v.x * v.y) * (v.z * v.w);
        // fold all 16 lanes of the DPP row into every lane (VALU only)
        p = ror_mul<0x121>(p);  // row_ror:1
        p = ror_mul<0x122>(p);  // row_ror:2
        p = ror_mul<0x124>(p);  // row_ror:4
        p = ror_mul<0x128>(p);  // row_ror:8
        if (store_lane) {
            const unsigned ooff = ooff0 + (unsigned)it * (NTHREADS / 16 * 4);
            __builtin_nontemporal_store(p, (float*)(outb + ooff));
        }
    }
}

extern "C" void kernel_launch(void* const* d_in, const int* in_sizes, int n_in,
                              void* d_out, int out_size, void* d_ws, size_t ws_size,
                              hipStream_t stream) {
    const char* xb = (const char*)d_in[0];
    char* outb = (char*)d_out;
    // in_sizes[0] == 16384*8192 == GRID*BLOCK*ITERS*4, exact — no tail.
    prodat_kernel<<<GRID, BLOCK, 0, stream>>>(xb, outb);
}